// Round 4
// baseline (1063.880 us; speedup 1.0000x reference)
//
#include <hip/hip_runtime.h>

#define H_ 128
#define T_ 1024
#define B_ 512
#define I_ 13
#define LOG2E 1.4426950408889634f

typedef _Float16 half8 __attribute__((ext_vector_type(8)));
typedef float float4_ __attribute__((ext_vector_type(4)));

static __device__ __forceinline__ float fast_rcp(float v) {
  return __builtin_amdgcn_rcpf(v);
}
static __device__ __forceinline__ float fast_exp2(float v) {
  return __builtin_amdgcn_exp2f(v);
}
static __device__ __forceinline__ float sigmoid_f(float v) {
  return fast_rcp(1.0f + fast_exp2(-LOG2E * v));
}
static __device__ __forceinline__ float tanh_f(float v) {
  return 2.0f * fast_rcp(1.0f + fast_exp2(-2.0f * LOG2E * v)) - 1.0f;
}

// lgkm-only workgroup barrier: LDS ordered, global loads/stores stay in flight
static __device__ __forceinline__ void wg_barrier_lds() {
  asm volatile("s_waitcnt lgkmcnt(0)\n\ts_barrier" ::: "memory");
}

// One WG per CU (256 WGs), 2 batch rows each, weights VGPR-resident.
// R2-verified math; R4 deltas: (1) depth-3 x register pipeline (issue at top,
// shift at bottom -> ~1.5 steps slack), (2) FC on wave 6 + softmax on wave 5
// one step later via tiny LDS logits buffer (no wave stacks MFMA + trans +
// shuffles + store), (3) accumulator bias init touches reg 0 only.
__global__ __launch_bounds__(512, 2) void lstm_fused(
    const float* __restrict__ x, const float* __restrict__ Wih,
    const float* __restrict__ Whh, const float* __restrict__ bih,
    const float* __restrict__ bhh, const float* __restrict__ Wfc,
    const float* __restrict__ bfc, float* __restrict__ out)
{
  // [buf][batchrow][168]: cols 0..127 h, 128..140 x, 141..167 zero pad
  __shared__ __align__(16) _Float16 abuf[2][2][168];
  // logits: [buf][batchrow][8] (cols 0..6 used)
  __shared__ __align__(16) float lgbuf[2][2][8];

  const int tid  = threadIdx.x;
  const int wave = tid >> 6;
  const int lane = tid & 63;
  const int n16  = lane & 15;
  const int quad = lane >> 4;
  const int wgb  = blockIdx.x * 2;

  // ---- W fragments: wave w owns gate tiles {w, w+8, w+16, w+24} ----
  // B layout (16x16x32): lane holds B[k = quad*8 + j][n = n16]
  half8 wfrag[4][5];
  float biasv[4];
  #pragma unroll
  for (int ti = 0; ti < 4; ++ti) {
    const int col = (wave + 8 * ti) * 16 + n16;
    biasv[ti] = bih[col] + bhh[col];
    #pragma unroll
    for (int kc = 0; kc < 5; ++kc) {
      half8 f;
      #pragma unroll
      for (int j = 0; j < 8; ++j) {
        const int k = kc * 32 + quad * 8 + j;
        float v = 0.0f;
        if (k < 128)            v = Whh[col * H_ + k];
        else if (k < 128 + I_)  v = Wih[col * I_ + (k - 128)];
        f[j] = (_Float16)v;
      }
      wfrag[ti][kc] = f;
    }
  }
  // FC tile (used by wave 6; loaded uniformly), k < 128 -> 4 chunks
  half8 wfc[4];
  const float biasfc = (n16 < 7) ? bfc[n16] : 0.0f;
  #pragma unroll
  for (int kc = 0; kc < 4; ++kc) {
    half8 f;
    #pragma unroll
    for (int j = 0; j < 8; ++j) {
      const int k = kc * 32 + quad * 8 + j;
      f[j] = (_Float16)((n16 < 7) ? Wfc[n16 * H_ + k] : 0.0f);
    }
    wfc[kc] = f;
  }

  // ---- init LDS: zero both A buffers + logits, write x(0) into buf 0 ----
  for (int i2 = tid; i2 < 2 * 2 * 168; i2 += 512)
    ((_Float16*)abuf)[i2] = (_Float16)0.0f;
  if (tid < 32) ((float*)lgbuf)[tid] = 0.0f;
  __syncthreads();
  if (tid < 26) {
    const int b = tid / 13, ii = tid - 13 * (tid / 13);
    abuf[0][b][128 + ii] = (_Float16)x[(wgb + b) * I_ + ii];
  }
  __syncthreads();

  float c_state = 0.0f;           // lanes 0..31: cell (row=quad, j=16w+n16)
  const bool aload = (n16 == 0) || (n16 == 4);
  const int  arow  = n16 >> 2;

  half8 af[5];
  {
    half8 z;
    #pragma unroll
    for (int j = 0; j < 8; ++j) z[j] = (_Float16)0.0f;
    #pragma unroll
    for (int kc = 0; kc < 5; ++kc) af[kc] = z;
  }

  // x pipeline (wave 4, lanes < 26): xn1 = x(t+1), xn2 = x(t+2)
  const int xb = (lane < 26) ? (lane / 13) : 0;
  const int xi = (lane < 26) ? (lane - 13 * (lane / 13)) : 0;
  float xn1 = 0.0f, xn2 = 0.0f;
  unsigned xoff = (unsigned)((wgb + xb) * I_ + xi);
  if (wave == 4 && lane < 26) {
    xn1 = x[xoff + (unsigned)(1 * B_ * I_)];
    xn2 = x[xoff + (unsigned)(2 * B_ * I_)];
  }
  xoff += (unsigned)(3 * B_ * I_);          // points at x(3)

  unsigned outidx = (unsigned)((wgb + quad) * 7 + n16);

  float4_ acc[4];
  #pragma unroll
  for (int ti = 0; ti < 4; ++ti)
    #pragma unroll
    for (int r = 0; r < 4; ++r) acc[ti][r] = 0.0f;
  float4_ accf;
  #pragma unroll
  for (int r = 0; r < 4; ++r) accf[r] = 0.0f;

  for (int t = 0; t <= T_ + 1; ++t) {
    // stage x(t+1) into next buffer EARLY (nobody reads that region this step;
    // prior readers of buffer (t+1)&1 finished at the last barrier)
    if (wave == 4 && lane < 26 && (t + 1) < T_)
      abuf[(t + 1) & 1][xb][128 + xi] = (_Float16)xn1;
    // issue x(t+3) now; consumed (reg shift) at the BOTTOM of this step
    float xnew = 0.0f;
    if (wave == 4 && lane < 26 && (t + 3) < T_) {
      xnew = x[xoff];
      xoff += (unsigned)(B_ * I_);
    }

    // A fragments for [h_t | x_t] (owner lanes n16==0 -> row 0, n16==4 -> row 1)
    if (aload) {
      #pragma unroll
      for (int kc = 0; kc < 5; ++kc)
        af[kc] = *(const half8*)&abuf[t & 1][arow][kc * 32 + quad * 8];
    }

    // ---- gates (all waves), t < T ----
    if (t < T_) {
      #pragma unroll
      for (int ti = 0; ti < 4; ++ti) acc[ti][0] = biasv[ti];
      #pragma unroll
      for (int kc = 0; kc < 5; ++kc) {
        #pragma unroll
        for (int ti = 0; ti < 4; ++ti)
          acc[ti] = __builtin_amdgcn_mfma_f32_16x16x32_f16(af[kc], wfrag[ti][kc], acc[ti], 0, 0, 0);
      }
      // cell update straight from accumulators (lanes 0..31, reg 0;
      // D row = quad*4 + reg -> rows 0,4 = batch rows 0,1)
      if (lane < 32) {
        const float iv = sigmoid_f(acc[0][0]);
        const float fv = sigmoid_f(acc[1][0]);
        const float gv = tanh_f(acc[2][0]);
        const float ov = sigmoid_f(acc[3][0]);
        c_state = fv * c_state + iv * gv;
        const float hv = ov * tanh_f(c_state);
        abuf[(t + 1) & 1][quad][16 * wave + n16] = (_Float16)hv;
      }
    }

    // ---- FC logits(h_t) on wave 6 -> lgbuf[t&1] ----
    if (wave == 6 && t <= T_) {
      accf[0] = biasfc;
      #pragma unroll
      for (int kc = 0; kc < 4; ++kc)
        accf = __builtin_amdgcn_mfma_f32_16x16x32_f16(af[kc], wfc[kc], accf, 0, 0, 0);
      if (lane < 32 && n16 < 7)
        lgbuf[t & 1][quad][n16] = accf[0];
    }

    // ---- softmax of logits(h_{t-1}) on wave 5 -> out row t-2 ----
    if (wave == 5 && t >= 2 && lane < 32) {
      const bool valid = (n16 < 7);
      const int pb = (t - 1) & 1;
      float lg = valid ? lgbuf[pb][quad][n16] : -3.0e38f;
      float vm = fmaxf(lg, __shfl_xor(lg, 1, 8));
      vm = fmaxf(vm, __shfl_xor(vm, 2, 8));
      vm = fmaxf(vm, __shfl_xor(vm, 4, 8));
      const float e = valid ? fast_exp2(LOG2E * (lg - vm)) : 0.0f;
      float s = e;
      s += __shfl_xor(s, 1, 8);
      s += __shfl_xor(s, 2, 8);
      s += __shfl_xor(s, 4, 8);
      if (valid) {
        out[outidx] = e * fast_rcp(s);
        outidx += (unsigned)(B_ * 7);
      }
    }

    // shift x pipeline LAST: the vmcnt wait for xnew lands ~1 step after issue
    if (wave == 4) {
      xn1 = xn2;
      xn2 = xnew;
    }

    wg_barrier_lds();
  }
}

extern "C" void kernel_launch(void* const* d_in, const int* in_sizes, int n_in,
                              void* d_out, int out_size, void* d_ws, size_t ws_size,
                              hipStream_t stream) {
  (void)in_sizes; (void)n_in; (void)out_size; (void)d_ws; (void)ws_size;
  const float* x   = (const float*)d_in[0];
  const float* Wih = (const float*)d_in[1];
  const float* Whh = (const float*)d_in[2];
  const float* bih = (const float*)d_in[3];
  const float* bhh = (const float*)d_in[4];
  const float* Wfc = (const float*)d_in[5];
  const float* bfc = (const float*)d_in[6];
  hipLaunchKernelGGL(lstm_fused, dim3(256), dim3(512), 0, stream,
                     x, Wih, Whh, bih, bhh, Wfc, bfc, (float*)d_out);
}

// Round 5
// 941.487 us; speedup vs baseline: 1.1300x; 1.1300x over previous
//
#include <hip/hip_runtime.h>

#define H_ 128
#define T_ 1024
#define B_ 512
#define I_ 13
#define LOG2E 1.4426950408889634f

typedef _Float16 half8 __attribute__((ext_vector_type(8)));
typedef float float4_ __attribute__((ext_vector_type(4)));

static __device__ __forceinline__ float fast_rcp(float v) {
  return __builtin_amdgcn_rcpf(v);
}
static __device__ __forceinline__ float fast_exp2(float v) {
  return __builtin_amdgcn_exp2f(v);
}
static __device__ __forceinline__ float sigmoid_f(float v) {
  return fast_rcp(1.0f + fast_exp2(-LOG2E * v));
}
static __device__ __forceinline__ float tanh_f(float v) {
  return 2.0f * fast_rcp(1.0f + fast_exp2(-2.0f * LOG2E * v)) - 1.0f;
}

// One WG per CU (256 WGs), 2 batch rows each, weights VGPR-resident.
// R5: the 1024-step loop contains ZERO vector-memory ops.
//   phase 0: x for this WG's 2 rows -> LDS (f16, 64 KB), zero-padded
//   loop:    gates MFMA + cell update (waves 0-7), FC logits -> LDS ring
//            (wave 6), one __syncthreads (vmcnt==0 so drain is free)
//   phase 2: softmax of 2048 logit rows from the ring -> global out
__global__ __launch_bounds__(512, 1) void lstm_fused(
    const float* __restrict__ x, const float* __restrict__ Wih,
    const float* __restrict__ Whh, const float* __restrict__ bih,
    const float* __restrict__ bhh, const float* __restrict__ Wfc,
    const float* __restrict__ bfc, float* __restrict__ out)
{
  // 64 KB: x(t) for both rows, slots 13..15 zero (pad to k-chunk width)
  __shared__ __align__(16) _Float16 xlds[T_][2][16];
  // 64 KB: logits ring, slot t holds logits for output row t (cols 0..6)
  __shared__ __align__(16) float lgring[T_][2][8];
  // 1.3 KB: double-buffered h (cols 0..127 used; stride 168 halfs)
  __shared__ __align__(16) _Float16 abuf[2][2][168];

  const int tid  = threadIdx.x;
  const int wave = tid >> 6;
  const int lane = tid & 63;
  const int n16  = lane & 15;
  const int quad = lane >> 4;
  const int wgb  = blockIdx.x * 2;

  // ---- W fragments: wave w owns gate tiles {w, w+8, w+16, w+24} ----
  // B layout (16x16x32): lane holds B[k = quad*8 + j][n = n16]
  half8 wfrag[4][5];
  float biasv[4];
  #pragma unroll
  for (int ti = 0; ti < 4; ++ti) {
    const int col = (wave + 8 * ti) * 16 + n16;
    biasv[ti] = bih[col] + bhh[col];
    #pragma unroll
    for (int kc = 0; kc < 5; ++kc) {
      half8 f;
      #pragma unroll
      for (int j = 0; j < 8; ++j) {
        const int k = kc * 32 + quad * 8 + j;
        float v = 0.0f;
        if (k < 128)            v = Whh[col * H_ + k];
        else if (k < 128 + I_)  v = Wih[col * I_ + (k - 128)];
        f[j] = (_Float16)v;
      }
      wfrag[ti][kc] = f;
    }
  }
  // FC tile (used by wave 6; loaded uniformly), k < 128 -> 4 chunks
  half8 wfc[4];
  const float biasfc = (n16 < 7) ? bfc[n16] : 0.0f;
  #pragma unroll
  for (int kc = 0; kc < 4; ++kc) {
    half8 f;
    #pragma unroll
    for (int j = 0; j < 8; ++j) {
      const int k = kc * 32 + quad * 8 + j;
      f[j] = (_Float16)((n16 < 7) ? Wfc[n16 * H_ + k] : 0.0f);
    }
    wfc[kc] = f;
  }

  // ---- phase 0: preload all x for this WG into LDS (f16), zero pads ----
  for (int idx = tid; idx < T_ * 2 * 16; idx += 512) {
    const int t  = idx >> 5;
    const int rw = (idx >> 4) & 1;
    const int ii = idx & 15;
    float v = 0.0f;
    if (ii < I_) v = x[((size_t)t * B_ + wgb + rw) * I_ + ii];
    xlds[t][rw][ii] = (_Float16)v;
  }
  for (int idx = tid; idx < 2 * 2 * 168; idx += 512)
    ((_Float16*)abuf)[idx] = (_Float16)0.0f;
  __syncthreads();

  float c_state = 0.0f;           // lanes 0..31: cell (row=quad, j=16w+n16)
  const bool aload = (n16 == 0) || (n16 == 4);
  const int  arow  = n16 >> 2;

  half8 af[5];
  {
    half8 z;
    #pragma unroll
    for (int j = 0; j < 8; ++j) z[j] = (_Float16)0.0f;
    #pragma unroll
    for (int kc = 0; kc < 5; ++kc) af[kc] = z;
  }

  float4_ acc[4];
  #pragma unroll
  for (int ti = 0; ti < 4; ++ti)
    #pragma unroll
    for (int r = 0; r < 4; ++r) acc[ti][r] = 0.0f;
  float4_ accf;
  #pragma unroll
  for (int r = 0; r < 4; ++r) accf[r] = 0.0f;

  // ---- phase 1: the recurrence. No vector-memory ops in this loop. ----
  for (int t = 0; t <= T_; ++t) {
    // A fragments: h chunks 0..3 from abuf, x chunk 4 from xlds[t]
    if (aload) {
      #pragma unroll
      for (int kc = 0; kc < 4; ++kc)
        af[kc] = *(const half8*)&abuf[t & 1][arow][kc * 32 + quad * 8];
      if (quad < 2 && t < T_)
        af[4] = *(const half8*)&xlds[t][arow][quad * 8];
    }

    if (t < T_) {
      #pragma unroll
      for (int ti = 0; ti < 4; ++ti) acc[ti][0] = biasv[ti];
      #pragma unroll
      for (int kc = 0; kc < 5; ++kc) {
        #pragma unroll
        for (int ti = 0; ti < 4; ++ti)
          acc[ti] = __builtin_amdgcn_mfma_f32_16x16x32_f16(af[kc], wfrag[ti][kc], acc[ti], 0, 0, 0);
      }
      // cell update from accumulators (lanes 0..31, reg 0;
      // D row = quad*4 + reg -> rows 0,4 = batch rows 0,1)
      if (lane < 32) {
        const float iv = sigmoid_f(acc[0][0]);
        const float fv = sigmoid_f(acc[1][0]);
        const float gv = tanh_f(acc[2][0]);
        const float ov = sigmoid_f(acc[3][0]);
        c_state = fv * c_state + iv * gv;
        const float hv = ov * tanh_f(c_state);
        abuf[(t + 1) & 1][quad][16 * wave + n16] = (_Float16)hv;
      }
    }

    // FC logits: af holds h_t here, h_t.Wfc = logits for output row t-1
    if (wave == 6 && t >= 1) {
      accf[0] = biasfc;
      #pragma unroll
      for (int kc = 0; kc < 4; ++kc)
        accf = __builtin_amdgcn_mfma_f32_16x16x32_f16(af[kc], wfc[kc], accf, 0, 0, 0);
      if (lane < 32 && n16 < 7)
        lgring[t - 1][quad][n16] = accf[0];
    }

    __syncthreads();
  }

  // ---- phase 2: softmax of all 2048 logit rows -> out ----
  for (int r = tid; r < T_ * 2; r += 512) {
    const int t = r >> 1;
    const int b = r & 1;
    float lg[7];
    float mx = -3.0e38f;
    #pragma unroll
    for (int k = 0; k < 7; ++k) {
      lg[k] = lgring[t][b][k];
      mx = fmaxf(mx, lg[k]);
    }
    float s = 0.0f;
    #pragma unroll
    for (int k = 0; k < 7; ++k) {
      lg[k] = fast_exp2(LOG2E * (lg[k] - mx));
      s += lg[k];
    }
    const float rs = fast_rcp(s);
    float* op = &out[((size_t)t * B_ + wgb + b) * 7];
    #pragma unroll
    for (int k = 0; k < 7; ++k) op[k] = lg[k] * rs;
  }
}

extern "C" void kernel_launch(void* const* d_in, const int* in_sizes, int n_in,
                              void* d_out, int out_size, void* d_ws, size_t ws_size,
                              hipStream_t stream) {
  (void)in_sizes; (void)n_in; (void)out_size; (void)d_ws; (void)ws_size;
  const float* x   = (const float*)d_in[0];
  const float* Wih = (const float*)d_in[1];
  const float* Whh = (const float*)d_in[2];
  const float* bih = (const float*)d_in[3];
  const float* bhh = (const float*)d_in[4];
  const float* Wfc = (const float*)d_in[5];
  const float* bfc = (const float*)d_in[6];
  hipLaunchKernelGGL(lstm_fused, dim3(256), dim3(512), 0, stream,
                     x, Wih, Whh, bih, bhh, Wfc, bfc, (float*)d_out);
}